// Round 2
// baseline (9998.557 us; speedup 1.0000x reference)
//
#include <hip/hip_runtime.h>

#define T_STEPS 2048
#define BATCH 8
#define HID 1024

// ws layout:
//   floats [0, 50331648)      x_proj repacked [b][t][gate][j]: ((b*2048+t)*3+g)*1024 + j
//   byte 201326592 (=192MiB): h double buffer, 2 x 4096 u64, each u64 packs TWO fp32 h
//                             values {hi = h(2q+1) clean, lo = h(2q) with bit30 = tag}.
//                             slot = parity*4096 + b*512 + q; production step s -> parity s&1,
//                             tagbit(s) = ((s>>1)&1)^1. |h|<1 (clamped) => real bit30 == 0.
//                             ws poison 0xAAAAAAAA has bit30=0 != tagbit(0)=1, so poison
//                             never validates. 64 KiB total.
//
// R-1batch+pack: 8 independent groups x 32 blocks; block owns (1 batch x 32 j).
// Sync domain 64 -> 32 blocks, staging 16KB -> 4KB/block (2 tagged u64 loads/thread),
// h store + out store are each one aligned 128-B line per block per step (no RFO),
// xproj stream is contiguous 12KB/group/step. group = bid&7 aligns each group with
// one XCD under round-robin dispatch (perf-only assumption, correctness unaffected).
#define XPROJ_F 50331648ull
#define HBUF64_BYTE_OFF 201326592ull

__device__ __forceinline__ float sigmoidf_(float x) {
    return 1.0f / (1.0f + __expf(-x));
}

// Relaxed AGENT-scope atomics lower to global_load/store ... sc1 — they read/
// write the Infinity Cache (the inter-XCD coherence point) with NO L2
// writeback/invalidate. An aligned 8B store is single-copy atomic, so the
// packed {tag|h_even, h_odd} packet is self-validating: no flags, no fences.
__device__ __forceinline__ unsigned long long ld_u64_agent(const unsigned long long* p) {
    return __hip_atomic_load(p, __ATOMIC_RELAXED, __HIP_MEMORY_SCOPE_AGENT);
}
__device__ __forceinline__ void st_u64_agent(unsigned long long* p, unsigned long long v) {
    __hip_atomic_store(p, v, __ATOMIC_RELAXED, __HIP_MEMORY_SCOPE_AGENT);
}

// ---------------- Phase 1: x_proj = x @ W_ih^T + b_ih ----------------
// 128x128 tile, BK=16, 256 threads, 8x8 micro-tile. Epilogue writes the
// [b][t][g][j] layout the scan wants (j-contiguous -> two float4 stores/row).
__global__ __launch_bounds__(256) void gemm_xproj(
        const float* __restrict__ x, const float* __restrict__ Wih,
        const float* __restrict__ bih, float* __restrict__ xproj) {
    __shared__ float a_lds[16][128];  // [k][m]
    __shared__ float b_lds[16][128];  // [k][n]
    const int tid = threadIdx.x;
    const int m0 = blockIdx.x * 128;
    const int n0 = blockIdx.y * 128;
    const int tx = tid & 15, ty = tid >> 4;

    float acc[8][8];
#pragma unroll
    for (int i = 0; i < 8; i++)
#pragma unroll
        for (int jj = 0; jj < 8; jj++) acc[i][jj] = 0.f;

    for (int k0 = 0; k0 < 1024; k0 += 16) {
#pragma unroll
        for (int l = 0; l < 2; l++) {
            const int c = tid + l * 256;
            const int row = c >> 2;
            const int f4 = c & 3;
            float4 av = *reinterpret_cast<const float4*>(
                x + (size_t)(m0 + row) * 1024 + k0 + f4 * 4);
            float4 bv = *reinterpret_cast<const float4*>(
                Wih + (size_t)(n0 + row) * 1024 + k0 + f4 * 4);
            a_lds[f4 * 4 + 0][row] = av.x; a_lds[f4 * 4 + 1][row] = av.y;
            a_lds[f4 * 4 + 2][row] = av.z; a_lds[f4 * 4 + 3][row] = av.w;
            b_lds[f4 * 4 + 0][row] = bv.x; b_lds[f4 * 4 + 1][row] = bv.y;
            b_lds[f4 * 4 + 2][row] = bv.z; b_lds[f4 * 4 + 3][row] = bv.w;
        }
        __syncthreads();
#pragma unroll
        for (int kk = 0; kk < 16; kk++) {
            float a[8], b[8];
            *reinterpret_cast<float4*>(&a[0]) =
                *reinterpret_cast<float4*>(&a_lds[kk][ty * 8]);
            *reinterpret_cast<float4*>(&a[4]) =
                *reinterpret_cast<float4*>(&a_lds[kk][ty * 8 + 4]);
            *reinterpret_cast<float4*>(&b[0]) =
                *reinterpret_cast<float4*>(&b_lds[kk][tx * 8]);
            *reinterpret_cast<float4*>(&b[4]) =
                *reinterpret_cast<float4*>(&b_lds[kk][tx * 8 + 4]);
#pragma unroll
            for (int i = 0; i < 8; i++)
#pragma unroll
                for (int jj = 0; jj < 8; jj++)
                    acc[i][jj] = fmaf(a[i], b[jj], acc[i][jj]);
        }
        __syncthreads();
    }

    float bias[8];
    *reinterpret_cast<float4*>(&bias[0]) =
        *reinterpret_cast<const float4*>(bih + n0 + tx * 8);
    *reinterpret_cast<float4*>(&bias[4]) =
        *reinterpret_cast<const float4*>(bih + n0 + tx * 8 + 4);
    // m = b*T + t; 128-row m-tiles never straddle a batch (T=2048 % 128 == 0).
    // n-tile (128 wide) never straddles a gate (1024 % 128 == 0).
    const int n_base = n0 + tx * 8;
    const int g = n_base >> 10;
    const int j0 = n_base & 1023;
#pragma unroll
    for (int i = 0; i < 8; i++) {
        const int m = m0 + ty * 8 + i;
        const int b = m >> 11;        // m / 2048
        const int t = m & 2047;
        float* dst = xproj + (((size_t)b * 2048 + t) * 3 + g) * 1024 + j0;
        float4 r0 = {acc[i][0] + bias[0], acc[i][1] + bias[1],
                     acc[i][2] + bias[2], acc[i][3] + bias[3]};
        float4 r1 = {acc[i][4] + bias[4], acc[i][5] + bias[5],
                     acc[i][6] + bias[6], acc[i][7] + bias[7]};
        *reinterpret_cast<float4*>(dst) = r0;
        *reinterpret_cast<float4*>(dst + 4) = r1;
    }
}

// ---------------- Phase 2: sequential GRU scan, 1 batch per group ----------------
// 256 blocks x 256 threads, co-resident (1 block/CU).
// group/batch b = bid&7 (8 groups x 32 blocks) — fully independent sync domains.
// Block owns j in [gb*32, gb*32+32), gb = bid>>3; wave owns 8 j. Per lane:
// 3 gates x 8 j x 16 k = 384 FMA, W_hh fragment = 384 VGPR, K split 64-way.
// Per step: prefetch gx (all lanes, broadcast) -> 2 pipelined packed-tagged u64
// loads -> retry stale -> unpack to LDS (double-buffered) -> sync -> matvec ->
// value-folding reduce (30 shuffles) -> gates on all lanes -> one 128-B packed
// h line + one 128-B out line per block.
__global__ __launch_bounds__(256, 1) void gru_scan(
        const float* __restrict__ Whh, const float* __restrict__ bhh,
        const float* __restrict__ xproj, float* __restrict__ out,
        unsigned long long* __restrict__ hbuf64) {
    __shared__ float hshare[2][HID];   // 8 KB, [parity][j]
    const int tid = threadIdx.x;
    const int bid = blockIdx.x;
    const int wave = tid >> 6;
    const int lane = tid & 63;
    const int b = bid & 7;                // batch / group
    const int gb = bid >> 3;              // block within group, 0..31
    const int jb_w = gb * 32 + wave * 8;  // wave's first j
    const int jw = jb_w + (lane & 7);     // this lane's output j

    // loop-invariant W_hh fragment: rows g*1024 + (jb_w+jj), k = lane + 64*i
    float wf[3][8][16];
#pragma unroll
    for (int g = 0; g < 3; g++)
#pragma unroll
        for (int jj = 0; jj < 8; jj++)
#pragma unroll
            for (int i = 0; i < 16; i++)
                wf[g][jj][i] =
                    Whh[(size_t)(g * 1024 + jb_w + jj) * 1024 + lane + 64 * i];

    const float bh0 = bhh[jw];
    const float bh1 = bhh[1024 + jw];
    const float bh2 = bhh[2048 + jw];
    const float CL = 0x1.fffffep-1f;   // largest float < 1: keeps bit30 == 0

    // ---- t = 0: h_prev = 0 -> g_h = b_hh ----
    {
        const size_t xb = ((size_t)b * 2048 + 0) * 3 * 1024 + jw;
        const float gxr = xproj[xb];
        const float gxz = xproj[xb + 1024];
        const float gxn = xproj[xb + 2048];
        const float r = sigmoidf_(gxr + bh0);
        const float z = sigmoidf_(gxz + bh1);
        const float n = tanhf(gxn + r * bh2);
        float hnew = (1.f - z) * n;
        hnew = fminf(fmaxf(hnew, -CL), CL);
        const float hodd = __shfl_xor(hnew, 1);   // even lane gets odd-j value
        const unsigned lo = __float_as_uint(hnew) | (1u << 30);  // tagbit(0)=1
        const unsigned hi = __float_as_uint(hodd);
        if (lane < 8) {
            if ((lane & 1) == 0)
                st_u64_agent(hbuf64 + (size_t)b * 512 + ((jb_w + lane) >> 1),
                             ((unsigned long long)hi << 32) | lo);
            out[((size_t)b * 2048 + 0) * 1024 + jw] = hnew;
        }
    }

    for (int t = 1; t < T_STEPS; t++) {
        // prefetch gx (broadcast loads, overlap the staging latency)
        const size_t xb = ((size_t)b * 2048 + t) * 3 * 1024 + jw;
        const float gxr = xproj[xb];
        const float gxz = xproj[xb + 1024];
        const float gxn = xproj[xb + 2048];

        // ---- stage h(t-1): 2 packed tagged u64 loads per thread ----
        const int par = (t - 1) & 1;
        const unsigned long long* src =
            hbuf64 + (size_t)par * 4096 + (size_t)b * 512;
        const unsigned expect = (((unsigned)(t - 1) >> 1) & 1u) ^ 1u;
        unsigned long long v0 = ld_u64_agent(src + tid);
        unsigned long long v1 = ld_u64_agent(src + tid + 256);
        for (;;) {
            const unsigned t0 = ((unsigned)(v0 >> 30)) & 1u;
            const unsigned t1 = ((unsigned)(v1 >> 30)) & 1u;
            if (((t0 ^ expect) | (t1 ^ expect)) == 0u) break;
            __builtin_amdgcn_s_sleep(1);
            if (t0 != expect) v0 = ld_u64_agent(src + tid);
            if (t1 != expect) v1 = ld_u64_agent(src + tid + 256);
        }
        {
            float2 p0, p1;
            p0.x = __uint_as_float((unsigned)v0 & 0xBFFFFFFFu);
            p0.y = __uint_as_float((unsigned)(v0 >> 32));
            p1.x = __uint_as_float((unsigned)v1 & 0xBFFFFFFFu);
            p1.y = __uint_as_float((unsigned)(v1 >> 32));
            *reinterpret_cast<float2*>(&hshare[par][2 * tid]) = p0;
            *reinterpret_cast<float2*>(&hshare[par][2 * tid + 512]) = p1;
        }
        __syncthreads();   // whole block validated + staged h(t-1)
        // (no trailing barrier: next step stages into the other parity half)

        const float hprev = hshare[par][jw];

        float acc[3][8];   // [g][jj]
#pragma unroll
        for (int g = 0; g < 3; g++)
#pragma unroll
            for (int q = 0; q < 8; q++) acc[g][q] = 0.f;
        {
            float hv[16];
#pragma unroll
            for (int i = 0; i < 16; i++)
                hv[i] = hshare[par][lane + 64 * i];
#pragma unroll
            for (int g = 0; g < 3; g++)
#pragma unroll
                for (int jj = 0; jj < 8; jj++)
#pragma unroll
                    for (int i = 0; i < 16; i++)
                        acc[g][jj] = fmaf(wf[g][jj][i], hv[i], acc[g][jj]);
        }

        // ---- value-folding reduce over the 64-way K split ----
        // 3 fold stages + 3 butterfly stages; lane l ends with the complete
        // sums for jj = l&7 (replicated across l>>3). 30 shuffles total.
        float a4[3][4];
#pragma unroll
        for (int g = 0; g < 3; g++)
#pragma unroll
            for (int k = 0; k < 4; k++) {
                const float e = acc[g][2 * k], o = acc[g][2 * k + 1];
                const float give = (lane & 1) ? e : o;
                const float keep = (lane & 1) ? o : e;
                a4[g][k] = keep + __shfl_xor(give, 1);
            }
        float a2[3][2];
#pragma unroll
        for (int g = 0; g < 3; g++)
#pragma unroll
            for (int k = 0; k < 2; k++) {
                const float e = a4[g][2 * k], o = a4[g][2 * k + 1];
                const float give = (lane & 2) ? e : o;
                const float keep = (lane & 2) ? o : e;
                a2[g][k] = keep + __shfl_xor(give, 2);
            }
        float a1[3];
#pragma unroll
        for (int g = 0; g < 3; g++) {
            const float e = a2[g][0], o = a2[g][1];
            const float give = (lane & 4) ? e : o;
            const float keep = (lane & 4) ? o : e;
            a1[g] = keep + __shfl_xor(give, 4);
        }
#pragma unroll
        for (int m = 8; m <= 32; m <<= 1)
#pragma unroll
            for (int g = 0; g < 3; g++) a1[g] += __shfl_xor(a1[g], m);

        // ---- gates on all lanes (a1 valid for jj = lane&7 on every lane) ----
        const float r = sigmoidf_(gxr + a1[0] + bh0);
        const float z = sigmoidf_(gxz + a1[1] + bh1);
        const float n = tanhf(gxn + r * (a1[2] + bh2));
        float hnew = (1.f - z) * n + z * hprev;
        hnew = fminf(fmaxf(hnew, -CL), CL);
        const float hodd = __shfl_xor(hnew, 1);
        const unsigned tagst = (((unsigned)t >> 1) & 1u) ^ 1u;
        const unsigned lo = __float_as_uint(hnew) | (tagst << 30);
        const unsigned hi = __float_as_uint(hodd);
        if (lane < 8) {
            if ((lane & 1) == 0)
                st_u64_agent(hbuf64 + (size_t)(t & 1) * 4096 + (size_t)b * 512 +
                                 ((jb_w + lane) >> 1),
                             ((unsigned long long)hi << 32) | lo);
            out[((size_t)b * 2048 + t) * 1024 + jw] = hnew;
        }
    }
}

extern "C" void kernel_launch(void* const* d_in, const int* in_sizes, int n_in,
                              void* d_out, int out_size, void* d_ws,
                              size_t ws_size, hipStream_t stream) {
    const float* x    = (const float*)d_in[0];
    const float* Wih  = (const float*)d_in[1];
    const float* bih  = (const float*)d_in[2];
    const float* Whh  = (const float*)d_in[3];
    const float* bhh  = (const float*)d_in[4];
    float* outp = (float*)d_out;

    float* xproj = (float*)d_ws;
    unsigned long long* hbuf64 =
        (unsigned long long*)((char*)d_ws + HBUF64_BYTE_OFF);

    dim3 g1(128, 24);   // M/128, N/128
    gemm_xproj<<<g1, 256, 0, stream>>>(x, Wih, bih, xproj);
    gru_scan<<<256, 256, 0, stream>>>(Whh, bhh, xproj, outp, hbuf64);
}